// Round 1
// baseline (885.176 us; speedup 1.0000x reference)
//
#include <hip/hip_runtime.h>
#include <math.h>

#define T_TOK 2048
#define DDIM 1024
#define HDIM 4096
#define NEXP 8

typedef unsigned short u16;
typedef __attribute__((ext_vector_type(4))) float f32x4;
typedef __attribute__((ext_vector_type(8))) __bf16 bf16x8;
typedef __attribute__((ext_vector_type(8))) unsigned short u16x8;
typedef __attribute__((ext_vector_type(4))) unsigned short u16x4;

__device__ __forceinline__ u16 f2bf(float f) {
  unsigned int u = __builtin_bit_cast(unsigned int, f);
  u += 0x7fffu + ((u >> 16) & 1u);   // round-to-nearest-even
  return (u16)(u >> 16);
}

// async global->LDS, 16B per lane. LDS dest must be wave-uniform base + lane*16.
__device__ __forceinline__ void stage16(const u16* g, u16* l) {
  __builtin_amdgcn_global_load_lds((__attribute__((address_space(1))) void*)g,
                                   (__attribute__((address_space(3))) void*)l,
                                   16, 0, 0);
}

// ---------------- prep: x fp32 -> bf16 ----------------
__global__ void cvt_x_kernel(const float* __restrict__ x, u16* __restrict__ xb) {
  int i = (blockIdx.x * 256 + threadIdx.x) * 8;  // 2M elems, grid 1024x256
  float4 a = *(const float4*)(x + i);
  float4 b = *(const float4*)(x + i + 4);
  u16x8 o;
  o[0] = f2bf(a.x); o[1] = f2bf(a.y); o[2] = f2bf(a.z); o[3] = f2bf(a.w);
  o[4] = f2bf(b.x); o[5] = f2bf(b.y); o[6] = f2bf(b.z); o[7] = f2bf(b.w);
  *(u16x8*)(xb + i) = o;
}

// ---------------- prep: per-expert transpose+cvt of Wg/Wv/Wo to [N][K] bf16 ----
__global__ void transpose_cvt_kernel(const float* __restrict__ Wg,
                                     const float* __restrict__ Wv,
                                     const float* __restrict__ Wo,
                                     u16* __restrict__ wgT, u16* __restrict__ wvT,
                                     u16* __restrict__ woT, int e) {
  __shared__ float lds[64][65];
  int bid = blockIdx.x;
  const float* src; u16* dst; int R, C, tt;
  if (bid < 1024)      { src = Wg + (size_t)e * DDIM * HDIM; dst = wgT; R = DDIM; C = HDIM; tt = bid; }
  else if (bid < 2048) { src = Wv + (size_t)e * DDIM * HDIM; dst = wvT; R = DDIM; C = HDIM; tt = bid - 1024; }
  else                 { src = Wo + (size_t)e * HDIM * DDIM; dst = woT; R = HDIM; C = DDIM; tt = bid - 2048; }
  int nrt = R >> 6;
  int r0 = (tt % nrt) << 6, c0 = (tt / nrt) << 6;
  int tid = threadIdx.x;
#pragma unroll
  for (int i = 0; i < 4; ++i) {
    int f4 = tid + 256 * i;            // 1024 float4 chunks = 64x64 tile
    int row = f4 >> 4, c4 = (f4 & 15) << 2;
    float4 v = *(const float4*)(src + (size_t)(r0 + row) * C + c0 + c4);
    lds[row][c4] = v.x; lds[row][c4 + 1] = v.y; lds[row][c4 + 2] = v.z; lds[row][c4 + 3] = v.w;
  }
  __syncthreads();
#pragma unroll
  for (int i = 0; i < 4; ++i) {
    int f4 = tid + 256 * i;
    int cc = f4 >> 4, r4 = (f4 & 15) << 2;
    u16x4 o;
    o[0] = f2bf(lds[r4][cc]);     o[1] = f2bf(lds[r4 + 1][cc]);
    o[2] = f2bf(lds[r4 + 2][cc]); o[3] = f2bf(lds[r4 + 3][cc]);
    *(u16x4*)(dst + (size_t)(c0 + cc) * R + r0 + r4) = o;
  }
}

// ---------------- GEMM A: g = x@Wg, v = x@Wv, h = gelu(g)*v*scale*cw -> bf16 ----
// 128x128 tile, BK=32, 4 waves (2x2), 64x64 per wave, m97-style 2-barrier loop.
__global__ void __launch_bounds__(256, 2)
gemm_gv_kernel(const u16* __restrict__ xb, const u16* __restrict__ wgT,
               const u16* __restrict__ wvT, const float* __restrict__ disp,
               const float* __restrict__ comb, const float* __restrict__ scale,
               u16* __restrict__ h, int e) {
  __shared__ u16 lds[3 * 128 * 32];
  u16* As = lds;
  u16* Bg = lds + 4096;
  u16* Bv = lds + 8192;

  const int tid = threadIdx.x;
  const int lane = tid & 63;
  const int wave = tid >> 6;
  const int wr = wave >> 1, wc = wave & 1;
  const int row0 = blockIdx.x * 128;   // tokens
  const int col0 = blockIdx.y * 128;   // H dim

  const int lrow = lane & 15;
  const int lkq = lane >> 4;           // 0..3
  const int lk = lkq << 3;

  f32x4 accg[4][4] = {};
  f32x4 accv[4][4] = {};

  const int c0 = tid, c1 = tid + 256;  // 512 16B-chunks per 128x32 tile
  const int ra0 = c0 >> 2, ka0 = (c0 & 3) << 3;
  const int ra1 = c1 >> 2, ka1 = (c1 & 3) << 3;

  const u16* gA0 = xb + (size_t)(row0 + ra0) * DDIM + ka0;
  const u16* gA1 = xb + (size_t)(row0 + ra1) * DDIM + ka1;
  const u16* gG0 = wgT + (size_t)(col0 + ra0) * DDIM + ka0;
  const u16* gG1 = wgT + (size_t)(col0 + ra1) * DDIM + ka1;
  const u16* gV0 = wvT + (size_t)(col0 + ra0) * DDIM + ka0;
  const u16* gV1 = wvT + (size_t)(col0 + ra1) * DDIM + ka1;
  u16* lA0 = As + c0 * 8; u16* lA1 = As + c1 * 8;
  u16* lG0 = Bg + c0 * 8; u16* lG1 = Bg + c1 * 8;
  u16* lV0 = Bv + c0 * 8; u16* lV1 = Bv + c1 * 8;

  for (int k0 = 0; k0 < DDIM; k0 += 32) {
    stage16(gA0 + k0, lA0); stage16(gA1 + k0, lA1);
    stage16(gG0 + k0, lG0); stage16(gG1 + k0, lG1);
    stage16(gV0 + k0, lV0); stage16(gV1 + k0, lV1);
    __syncthreads();  // drains vmcnt -> tile resident
    bf16x8 a[4], bg[4], bv[4];
#pragma unroll
    for (int m = 0; m < 4; ++m)
      a[m] = *(const bf16x8*)&As[(64 * wr + 16 * m + lrow) * 32 + lk];
#pragma unroll
    for (int n = 0; n < 4; ++n) {
      bg[n] = *(const bf16x8*)&Bg[(64 * wc + 16 * n + lrow) * 32 + lk];
      bv[n] = *(const bf16x8*)&Bv[(64 * wc + 16 * n + lrow) * 32 + lk];
    }
#pragma unroll
    for (int m = 0; m < 4; ++m)
#pragma unroll
      for (int n = 0; n < 4; ++n) {
        accg[m][n] = __builtin_amdgcn_mfma_f32_16x16x32_bf16(a[m], bg[n], accg[m][n], 0, 0, 0);
        accv[m][n] = __builtin_amdgcn_mfma_f32_16x16x32_bf16(a[m], bv[n], accv[m][n], 0, 0, 0);
      }
    __syncthreads();  // all reads done before next stage overwrites
  }

  const float s_e = scale[e];
#pragma unroll
  for (int m = 0; m < 4; ++m) {
#pragma unroll
    for (int r = 0; r < 4; ++r) {
      const int t = row0 + 64 * wr + 16 * m + (lkq << 2) + r;
      const float dv = disp[t * NEXP + e];
      const float cv = comb[t * NEXP + e];
      const float s = (dv > 0.0f) ? cv * s_e : 0.0f;
#pragma unroll
      for (int n = 0; n < 4; ++n) {
        const float g = accg[m][n][r];
        const float v = accv[m][n][r];
        const float ge = 0.5f * g * (1.0f + erff(g * 0.70710678f));  // exact gelu
        h[(size_t)t * HDIM + col0 + 64 * wc + 16 * n + lrow] = f2bf(ge * v * s);
      }
    }
  }
}

// ---------------- GEMM B: P[ks] (+)= h @ Wo, split-K=2, accumulated over experts
__global__ void __launch_bounds__(256, 2)
gemm_out_kernel(const u16* __restrict__ h, const u16* __restrict__ woT,
                float* __restrict__ P, int e) {
  __shared__ u16 lds[2 * 128 * 32];
  u16* As = lds;
  u16* Bs = lds + 4096;

  const int tid = threadIdx.x;
  const int lane = tid & 63;
  const int wave = tid >> 6;
  const int wr = wave >> 1, wc = wave & 1;
  const int row0 = blockIdx.x * 128;   // tokens
  const int col0 = blockIdx.y * 128;   // D dim
  const int kbase = blockIdx.z * 2048; // split-K

  const int lrow = lane & 15;
  const int lkq = lane >> 4;
  const int lk = lkq << 3;

  f32x4 acc[4][4] = {};

  const int c0 = tid, c1 = tid + 256;
  const int ra0 = c0 >> 2, ka0 = (c0 & 3) << 3;
  const int ra1 = c1 >> 2, ka1 = (c1 & 3) << 3;

  const u16* gA0 = h + (size_t)(row0 + ra0) * HDIM + kbase + ka0;
  const u16* gA1 = h + (size_t)(row0 + ra1) * HDIM + kbase + ka1;
  const u16* gB0 = woT + (size_t)(col0 + ra0) * HDIM + kbase + ka0;
  const u16* gB1 = woT + (size_t)(col0 + ra1) * HDIM + kbase + ka1;
  u16* lA0 = As + c0 * 8; u16* lA1 = As + c1 * 8;
  u16* lB0 = Bs + c0 * 8; u16* lB1 = Bs + c1 * 8;

  for (int k0 = 0; k0 < 2048; k0 += 32) {
    stage16(gA0 + k0, lA0); stage16(gA1 + k0, lA1);
    stage16(gB0 + k0, lB0); stage16(gB1 + k0, lB1);
    __syncthreads();
    bf16x8 a[4], b[4];
#pragma unroll
    for (int m = 0; m < 4; ++m)
      a[m] = *(const bf16x8*)&As[(64 * wr + 16 * m + lrow) * 32 + lk];
#pragma unroll
    for (int n = 0; n < 4; ++n)
      b[n] = *(const bf16x8*)&Bs[(64 * wc + 16 * n + lrow) * 32 + lk];
#pragma unroll
    for (int m = 0; m < 4; ++m)
#pragma unroll
      for (int n = 0; n < 4; ++n)
        acc[m][n] = __builtin_amdgcn_mfma_f32_16x16x32_bf16(a[m], b[n], acc[m][n], 0, 0, 0);
    __syncthreads();
  }

  float* Pp = P + (size_t)blockIdx.z * (T_TOK * DDIM);
#pragma unroll
  for (int m = 0; m < 4; ++m) {
#pragma unroll
    for (int r = 0; r < 4; ++r) {
      const int t = row0 + 64 * wr + 16 * m + (lkq << 2) + r;
#pragma unroll
      for (int n = 0; n < 4; ++n) {
        const size_t idx = (size_t)t * DDIM + col0 + 64 * wc + 16 * n + lrow;
        if (e == 0) Pp[idx] = acc[m][n][r];
        else        Pp[idx] += acc[m][n][r];
      }
    }
  }
}

// ---------------- final: out = P0 + P1 ----------------
__global__ void reduce_out_kernel(const float* __restrict__ P, float* __restrict__ out) {
  int i = blockIdx.x * 256 + threadIdx.x;  // float4 index, grid 2048x256
  float4 a = ((const float4*)P)[i];
  float4 b = ((const float4*)P)[i + (T_TOK * DDIM / 4)];
  float4 o;
  o.x = a.x + b.x; o.y = a.y + b.y; o.z = a.z + b.z; o.w = a.w + b.w;
  ((float4*)out)[i] = o;
}

extern "C" void kernel_launch(void* const* d_in, const int* in_sizes, int n_in,
                              void* d_out, int out_size, void* d_ws, size_t ws_size,
                              hipStream_t stream) {
  const float* tokens = (const float*)d_in[0];
  const float* disp   = (const float*)d_in[1];
  const float* comb   = (const float*)d_in[2];
  const float* Wg     = (const float*)d_in[3];
  const float* Wv     = (const float*)d_in[4];
  const float* Wo     = (const float*)d_in[5];
  const float* scale  = (const float*)d_in[6];
  float* out = (float*)d_out;

  char* ws = (char*)d_ws;
  u16* xb   = (u16*)(ws);                                // 4 MB
  u16* wgT  = (u16*)(ws + (size_t)4  * 1024 * 1024);     // 8 MB
  u16* wvT  = (u16*)(ws + (size_t)12 * 1024 * 1024);     // 8 MB
  u16* woT  = (u16*)(ws + (size_t)20 * 1024 * 1024);     // 8 MB
  u16* hbuf = (u16*)(ws + (size_t)28 * 1024 * 1024);     // 16 MB
  float* P  = (float*)(ws + (size_t)44 * 1024 * 1024);   // 16 MB (2 split-K partials)

  cvt_x_kernel<<<1024, 256, 0, stream>>>(tokens, xb);
  for (int e = 0; e < NEXP; ++e) {
    transpose_cvt_kernel<<<3072, 256, 0, stream>>>(Wg, Wv, Wo, wgT, wvT, woT, e);
    gemm_gv_kernel<<<dim3(16, 32), 256, 0, stream>>>(xb, wgT, wvT, disp, comb, scale, hbuf, e);
    gemm_out_kernel<<<dim3(16, 8, 2), 256, 0, stream>>>(hbuf, woT, P, e);
  }
  reduce_out_kernel<<<2048, 256, 0, stream>>>(P, out);
}

// Round 2
// 753.560 us; speedup vs baseline: 1.1747x; 1.1747x over previous
//
#include <hip/hip_runtime.h>
#include <math.h>

#define T_TOK 2048
#define DDIM 1024
#define HDIM 4096
#define NEXP 8
#define KTOT (NEXP * HDIM)   // 32768, out-GEMM K
#define NSPLIT 4

typedef unsigned short u16;
typedef __attribute__((ext_vector_type(4))) float f32x4;
typedef __attribute__((ext_vector_type(8))) __bf16 bf16x8;
typedef __attribute__((ext_vector_type(8))) unsigned short u16x8;
typedef __attribute__((ext_vector_type(4))) unsigned short u16x4;

__device__ __forceinline__ u16 f2bf(float f) {
  unsigned int u = __builtin_bit_cast(unsigned int, f);
  u += 0x7fffu + ((u >> 16) & 1u);   // round-to-nearest-even
  return (u16)(u >> 16);
}

// async global->LDS, 16B per lane. LDS dest must be wave-uniform base + lane*16.
__device__ __forceinline__ void stage16(const u16* g, u16* l) {
  __builtin_amdgcn_global_load_lds((__attribute__((address_space(1))) void*)g,
                                   (__attribute__((address_space(3))) void*)l,
                                   16, 0, 0);
}

// ---------------- prep: x fp32 -> bf16 ----------------
__global__ void cvt_x_kernel(const float* __restrict__ x, u16* __restrict__ xb) {
  int i = (blockIdx.x * 256 + threadIdx.x) * 8;  // 2M elems, grid 1024x256
  float4 a = *(const float4*)(x + i);
  float4 b = *(const float4*)(x + i + 4);
  u16x8 o;
  o[0] = f2bf(a.x); o[1] = f2bf(a.y); o[2] = f2bf(a.z); o[3] = f2bf(a.w);
  o[4] = f2bf(b.x); o[5] = f2bf(b.y); o[6] = f2bf(b.z); o[7] = f2bf(b.w);
  *(u16x8*)(xb + i) = o;
}

// ---------------- prep: ALL experts' Wg/Wv/Wo transpose+cvt, one launch ----
// wgT/wvT: [E][H][D] bf16 (y = x@W -> B rows are N=H, K=D contiguous)
// woT2:    [D][E*H] bf16 (single big out-GEMM, K = E*H contiguous)
__global__ void transpose_all_kernel(const float* __restrict__ Wg,
                                     const float* __restrict__ Wv,
                                     const float* __restrict__ Wo,
                                     u16* __restrict__ wgT, u16* __restrict__ wvT,
                                     u16* __restrict__ woT2) {
  __shared__ float lds[64][65];
  const int bid = blockIdx.x;           // 24576 blocks = 8e * 3mat * 1024 tiles
  const int e = bid / 3072;
  const int r = bid % 3072;
  const int which = r >> 10;            // 0=Wg 1=Wv 2=Wo
  const int tt = r & 1023;
  const float* src; int R, C;
  if (which == 2) { src = Wo + (size_t)e * HDIM * DDIM; R = HDIM; C = DDIM; }
  else            { src = (which ? Wv : Wg) + (size_t)e * DDIM * HDIM; R = DDIM; C = HDIM; }
  const int nrt = R >> 6;
  const int r0 = (tt % nrt) << 6, c0 = (tt / nrt) << 6;
  const int tid = threadIdx.x;
#pragma unroll
  for (int i = 0; i < 4; ++i) {
    int f4 = tid + 256 * i;             // 1024 float4 chunks = 64x64 tile
    int row = f4 >> 4, c4 = (f4 & 15) << 2;
    float4 v = *(const float4*)(src + (size_t)(r0 + row) * C + c0 + c4);
    lds[row][c4] = v.x; lds[row][c4 + 1] = v.y; lds[row][c4 + 2] = v.z; lds[row][c4 + 3] = v.w;
  }
  __syncthreads();
#pragma unroll
  for (int i = 0; i < 4; ++i) {
    int f4 = tid + 256 * i;
    int cc = f4 >> 4, r4 = (f4 & 15) << 2;
    u16x4 o;
    o[0] = f2bf(lds[r4][cc]);     o[1] = f2bf(lds[r4 + 1][cc]);
    o[2] = f2bf(lds[r4 + 2][cc]); o[3] = f2bf(lds[r4 + 3][cc]);
    u16* dst;
    if (which == 2) dst = woT2 + (size_t)(c0 + cc) * KTOT + e * HDIM + r0 + r4;
    else dst = (which ? wvT : wgT) + (size_t)e * HDIM * DDIM + (size_t)(c0 + cc) * DDIM + r0 + r4;
    *(u16x4*)dst = o;
  }
}

// ---------------- GEMM A: g = x@Wg, v = x@Wv, h = gelu(g)*v*scale*cw -> bf16 ----
// 128x128 tile, BK=32, 4 waves (2x2), 64x64/wave. blockIdx.z = expert.
__global__ void __launch_bounds__(256, 2)
gemm_gv_kernel(const u16* __restrict__ xb, const u16* __restrict__ wgT_all,
               const u16* __restrict__ wvT_all, const float* __restrict__ disp,
               const float* __restrict__ comb, const float* __restrict__ scale,
               u16* __restrict__ h) {
  __shared__ u16 lds[3 * 128 * 32];
  u16* As = lds;
  u16* Bg = lds + 4096;
  u16* Bv = lds + 8192;

  const int e = blockIdx.z;
  const u16* wgT = wgT_all + (size_t)e * HDIM * DDIM;
  const u16* wvT = wvT_all + (size_t)e * HDIM * DDIM;

  const int tid = threadIdx.x;
  const int lane = tid & 63;
  const int wave = tid >> 6;
  const int wr = wave >> 1, wc = wave & 1;
  const int row0 = blockIdx.x * 128;   // tokens
  const int col0 = blockIdx.y * 128;   // H dim

  const int lrow = lane & 15;
  const int lkq = lane >> 4;           // 0..3
  const int lk = lkq << 3;

  f32x4 accg[4][4] = {};
  f32x4 accv[4][4] = {};

  const int c0 = tid, c1 = tid + 256;  // 512 16B-chunks per 128x32 tile
  const int ra0 = c0 >> 2, ka0 = (c0 & 3) << 3;
  const int ra1 = c1 >> 2, ka1 = (c1 & 3) << 3;

  const u16* gA0 = xb + (size_t)(row0 + ra0) * DDIM + ka0;
  const u16* gA1 = xb + (size_t)(row0 + ra1) * DDIM + ka1;
  const u16* gG0 = wgT + (size_t)(col0 + ra0) * DDIM + ka0;
  const u16* gG1 = wgT + (size_t)(col0 + ra1) * DDIM + ka1;
  const u16* gV0 = wvT + (size_t)(col0 + ra0) * DDIM + ka0;
  const u16* gV1 = wvT + (size_t)(col0 + ra1) * DDIM + ka1;
  u16* lA0 = As + c0 * 8; u16* lA1 = As + c1 * 8;
  u16* lG0 = Bg + c0 * 8; u16* lG1 = Bg + c1 * 8;
  u16* lV0 = Bv + c0 * 8; u16* lV1 = Bv + c1 * 8;

  for (int k0 = 0; k0 < DDIM; k0 += 32) {
    stage16(gA0 + k0, lA0); stage16(gA1 + k0, lA1);
    stage16(gG0 + k0, lG0); stage16(gG1 + k0, lG1);
    stage16(gV0 + k0, lV0); stage16(gV1 + k0, lV1);
    __syncthreads();  // drains vmcnt -> tile resident
    bf16x8 a[4], bg[4], bv[4];
#pragma unroll
    for (int m = 0; m < 4; ++m)
      a[m] = *(const bf16x8*)&As[(64 * wr + 16 * m + lrow) * 32 + lk];
#pragma unroll
    for (int n = 0; n < 4; ++n) {
      bg[n] = *(const bf16x8*)&Bg[(64 * wc + 16 * n + lrow) * 32 + lk];
      bv[n] = *(const bf16x8*)&Bv[(64 * wc + 16 * n + lrow) * 32 + lk];
    }
#pragma unroll
    for (int m = 0; m < 4; ++m)
#pragma unroll
      for (int n = 0; n < 4; ++n) {
        accg[m][n] = __builtin_amdgcn_mfma_f32_16x16x32_bf16(a[m], bg[n], accg[m][n], 0, 0, 0);
        accv[m][n] = __builtin_amdgcn_mfma_f32_16x16x32_bf16(a[m], bv[n], accv[m][n], 0, 0, 0);
      }
    __syncthreads();  // all reads done before next stage overwrites
  }

  const float s_e = scale[e];
#pragma unroll
  for (int m = 0; m < 4; ++m) {
#pragma unroll
    for (int r = 0; r < 4; ++r) {
      const int t = row0 + 64 * wr + 16 * m + (lkq << 2) + r;
      const float dv = disp[t * NEXP + e];
      const float cv = comb[t * NEXP + e];
      const float s = (dv > 0.0f) ? cv * s_e : 0.0f;
#pragma unroll
      for (int n = 0; n < 4; ++n) {
        const float g = accg[m][n][r];
        const float v = accv[m][n][r];
        const float ge = 0.5f * g * (1.0f + erff(g * 0.70710678f));  // exact gelu
        h[(size_t)t * KTOT + e * HDIM + col0 + 64 * wc + 16 * n + lrow] = f2bf(ge * v * s);
      }
    }
  }
}

// ---------------- GEMM B: out = h[T][EH] @ woT2[D][EH]^T, split-K over z ----
__global__ void __launch_bounds__(256, 2)
gemm_out_kernel(const u16* __restrict__ h, const u16* __restrict__ woT2,
                float* __restrict__ P) {
  __shared__ u16 lds[2 * 128 * 32];
  u16* As = lds;
  u16* Bs = lds + 4096;

  const int tid = threadIdx.x;
  const int lane = tid & 63;
  const int wave = tid >> 6;
  const int wr = wave >> 1, wc = wave & 1;
  const int row0 = blockIdx.x * 128;            // tokens
  const int col0 = blockIdx.y * 128;            // D dim
  const int kbase = blockIdx.z * (KTOT / NSPLIT);

  const int lrow = lane & 15;
  const int lkq = lane >> 4;
  const int lk = lkq << 3;

  f32x4 acc[4][4] = {};

  const int c0 = tid, c1 = tid + 256;
  const int ra0 = c0 >> 2, ka0 = (c0 & 3) << 3;
  const int ra1 = c1 >> 2, ka1 = (c1 & 3) << 3;

  const u16* gA0 = h + (size_t)(row0 + ra0) * KTOT + kbase + ka0;
  const u16* gA1 = h + (size_t)(row0 + ra1) * KTOT + kbase + ka1;
  const u16* gB0 = woT2 + (size_t)(col0 + ra0) * KTOT + kbase + ka0;
  const u16* gB1 = woT2 + (size_t)(col0 + ra1) * KTOT + kbase + ka1;
  u16* lA0 = As + c0 * 8; u16* lA1 = As + c1 * 8;
  u16* lB0 = Bs + c0 * 8; u16* lB1 = Bs + c1 * 8;

  for (int k0 = 0; k0 < KTOT / NSPLIT; k0 += 32) {
    stage16(gA0 + k0, lA0); stage16(gA1 + k0, lA1);
    stage16(gB0 + k0, lB0); stage16(gB1 + k0, lB1);
    __syncthreads();
    bf16x8 a[4], b[4];
#pragma unroll
    for (int m = 0; m < 4; ++m)
      a[m] = *(const bf16x8*)&As[(64 * wr + 16 * m + lrow) * 32 + lk];
#pragma unroll
    for (int n = 0; n < 4; ++n)
      b[n] = *(const bf16x8*)&Bs[(64 * wc + 16 * n + lrow) * 32 + lk];
#pragma unroll
    for (int m = 0; m < 4; ++m)
#pragma unroll
      for (int n = 0; n < 4; ++n)
        acc[m][n] = __builtin_amdgcn_mfma_f32_16x16x32_bf16(a[m], b[n], acc[m][n], 0, 0, 0);
    __syncthreads();
  }

  float* Pp = P + (size_t)blockIdx.z * (T_TOK * DDIM);
#pragma unroll
  for (int m = 0; m < 4; ++m) {
#pragma unroll
    for (int r = 0; r < 4; ++r) {
      const int t = row0 + 64 * wr + 16 * m + (lkq << 2) + r;
#pragma unroll
      for (int n = 0; n < 4; ++n)
        Pp[(size_t)t * DDIM + col0 + 64 * wc + 16 * n + lrow] = acc[m][n][r];
    }
  }
}

// ---------------- final: out = sum of NSPLIT partials ----------------
__global__ void reduce_out_kernel(const float* __restrict__ P, float* __restrict__ out) {
  int i = blockIdx.x * 256 + threadIdx.x;  // float4 index, grid 2048x256
  float4 a = ((const float4*)P)[i];
#pragma unroll
  for (int s = 1; s < NSPLIT; ++s) {
    float4 b = ((const float4*)P)[i + s * (T_TOK * DDIM / 4)];
    a.x += b.x; a.y += b.y; a.z += b.z; a.w += b.w;
  }
  ((float4*)out)[i] = a;
}

extern "C" void kernel_launch(void* const* d_in, const int* in_sizes, int n_in,
                              void* d_out, int out_size, void* d_ws, size_t ws_size,
                              hipStream_t stream) {
  const float* tokens = (const float*)d_in[0];
  const float* disp   = (const float*)d_in[1];
  const float* comb   = (const float*)d_in[2];
  const float* Wg     = (const float*)d_in[3];
  const float* Wv     = (const float*)d_in[4];
  const float* Wo     = (const float*)d_in[5];
  const float* scale  = (const float*)d_in[6];
  float* out = (float*)d_out;

  char* ws = (char*)d_ws;
  const size_t MB = 1024 * 1024;
  u16* xb    = (u16*)(ws);              // 4 MB   [T][D] bf16
  u16* wgT   = (u16*)(ws + 4   * MB);   // 64 MB  [E][H][D]
  u16* wvT   = (u16*)(ws + 68  * MB);   // 64 MB  [E][H][D]
  u16* woT2  = (u16*)(ws + 132 * MB);   // 64 MB  [D][E*H]
  u16* hbuf  = (u16*)(ws + 196 * MB);   // 128 MB [T][E*H]
  float* P   = (float*)(ws + 324 * MB); // 32 MB  NSPLIT x [T][D] fp32

  cvt_x_kernel<<<1024, 256, 0, stream>>>(tokens, xb);
  transpose_all_kernel<<<24576, 256, 0, stream>>>(Wg, Wv, Wo, wgT, wvT, woT2);
  gemm_gv_kernel<<<dim3(16, 32, NEXP), 256, 0, stream>>>(xb, wgT, wvT, disp, comb, scale, hbuf);
  gemm_out_kernel<<<dim3(16, 8, NSPLIT), 256, 0, stream>>>(hbuf, woT2, P);
  reduce_out_kernel<<<2048, 256, 0, stream>>>(P, out);
}

// Round 3
// 589.515 us; speedup vs baseline: 1.5015x; 1.2783x over previous
//
#include <hip/hip_runtime.h>
#include <math.h>

#define T_TOK 2048
#define DDIM 1024
#define HDIM 4096
#define NEXP 8
#define NPRIME 8192            // 2*HDIM interleaved g/v cols per expert
#define KTOT (NEXP * HDIM)     // 32768
#define NSPLIT 4

typedef unsigned short u16;
typedef __attribute__((ext_vector_type(4))) float f32x4;
typedef __attribute__((ext_vector_type(8))) __bf16 bf16x8;
typedef __attribute__((ext_vector_type(8))) unsigned short u16x8;
typedef __attribute__((ext_vector_type(4))) unsigned short u16x4;

__device__ __forceinline__ u16 f2bf(float f) {
  unsigned int u = __builtin_bit_cast(unsigned int, f);
  u += 0x7fffu + ((u >> 16) & 1u);   // round-to-nearest-even
  return (u16)(u >> 16);
}

__device__ __forceinline__ void stage16(const u16* g, u16* l) {
  __builtin_amdgcn_global_load_lds((__attribute__((address_space(1))) void*)g,
                                   (__attribute__((address_space(3))) void*)l,
                                   16, 0, 0);
}

// ---------------- prep: x fp32 -> bf16 ----------------
__global__ void cvt_x_kernel(const float* __restrict__ x, u16* __restrict__ xb) {
  int i = (blockIdx.x * 256 + threadIdx.x) * 8;
  float4 a = *(const float4*)(x + i);
  float4 b = *(const float4*)(x + i + 4);
  u16x8 o;
  o[0] = f2bf(a.x); o[1] = f2bf(a.y); o[2] = f2bf(a.z); o[3] = f2bf(a.w);
  o[4] = f2bf(b.x); o[5] = f2bf(b.y); o[6] = f2bf(b.z); o[7] = f2bf(b.w);
  *(u16x8*)(xb + i) = o;
}

// ---------------- prep: transpose+cvt all experts ----------------
// wgvT: [E][N'=8192][D] bf16, Wg/Wv column-interleaved in 16-groups:
//   row' = (h>>4)*32 + which*16 + (h&15)   (which: 0=g, 1=v)
// woT2: [D][E*H] bf16
__global__ void transpose_all_kernel(const float* __restrict__ Wg,
                                     const float* __restrict__ Wv,
                                     const float* __restrict__ Wo,
                                     u16* __restrict__ wgvT, u16* __restrict__ woT2) {
  __shared__ float lds[64][65];
  const int bid = blockIdx.x;           // 24576 blocks = 8e * 3mat * 1024 tiles
  const int e = bid / 3072;
  const int r = bid % 3072;
  const int which = r >> 10;            // 0=Wg 1=Wv 2=Wo
  const int tt = r & 1023;
  const float* src; int R, C;
  if (which == 2) { src = Wo + (size_t)e * HDIM * DDIM; R = HDIM; C = DDIM; }
  else            { src = (which ? Wv : Wg) + (size_t)e * DDIM * HDIM; R = DDIM; C = HDIM; }
  const int nrt = R >> 6;
  const int r0 = (tt % nrt) << 6, c0 = (tt / nrt) << 6;
  const int tid = threadIdx.x;
#pragma unroll
  for (int i = 0; i < 4; ++i) {
    int f4 = tid + 256 * i;
    int row = f4 >> 4, c4 = (f4 & 15) << 2;
    float4 v = *(const float4*)(src + (size_t)(r0 + row) * C + c0 + c4);
    lds[row][c4] = v.x; lds[row][c4 + 1] = v.y; lds[row][c4 + 2] = v.z; lds[row][c4 + 3] = v.w;
  }
  __syncthreads();
#pragma unroll
  for (int i = 0; i < 4; ++i) {
    int f4 = tid + 256 * i;
    int cc = f4 >> 4, r4 = (f4 & 15) << 2;
    u16x4 o;
    o[0] = f2bf(lds[r4][cc]);     o[1] = f2bf(lds[r4 + 1][cc]);
    o[2] = f2bf(lds[r4 + 2][cc]); o[3] = f2bf(lds[r4 + 3][cc]);
    u16* dst;
    if (which == 2) {
      dst = woT2 + (size_t)(c0 + cc) * KTOT + e * HDIM + r0 + r4;
    } else {
      int h = c0 + cc;
      int rowp = ((h >> 4) << 5) + which * 16 + (h & 15);
      dst = wgvT + (size_t)e * NPRIME * DDIM + (size_t)rowp * DDIM + r0 + r4;
    }
    *(u16x4*)dst = o;
  }
}

// =================================================================
// GEMM core geometry: BM=256, BN=128, BK=64, 8 waves (4M x 2N),
// per-wave 64x64, 3 LDS buffers, counted vmcnt pipeline.
// LDS buffer: A 256x64 (16384 elems) + B 128x64 (8192) = 24576 u16 = 48 KB.
// Staging: 3072 16B-chunks / 512 thr = 6 per thread -> vmcnt(6) steady state.
// Swizzle: LDS slot s (8B groups within 64-elem row) holds global slot
// s ^ (row&7); read applies same XOR -> 2-way bank aliasing (free).
// =================================================================

// ---------------- GEMM A: h = (gelu(x@Wg) * (x@Wv)) * scale * cw ----------------
__global__ void __launch_bounds__(512, 2)
gemm_gv_kernel(const u16* __restrict__ xb, const u16* __restrict__ wgvT,
               const float* __restrict__ disp, const float* __restrict__ comb,
               const float* __restrict__ scale, u16* __restrict__ h) {
  __shared__ u16 lds[3 * 24576];

  // bijective XCD swizzle: nwg=4096 -> XCD i owns expert i entirely
  const int bid = blockIdx.x;
  const int wg = (bid & 7) * 512 + (bid >> 3);
  const int e  = wg >> 9;
  const int nt = (wg >> 3) & 63;   // N'-tile (128 cols of 8192)
  const int mt = wg & 7;           // M-tile (256 rows of 2048)

  const int tid = threadIdx.x;
  const int lane = tid & 63;
  const int wave = tid >> 6;
  const int wr = wave >> 1;        // 0..3 (M)
  const int wc = wave & 1;         // 0..1 (N)
  const int l15 = lane & 15;
  const int lkq = lane >> 4;

  const u16* Ag = xb;                                       // [2048][1024]
  const u16* Bg = wgvT + (size_t)e * NPRIME * DDIM;         // [8192][1024]
  const int Am0 = mt * 256;
  const int Bn0 = nt * 128;

  // per-thread staging descriptors (6 chunks: 4 A + 2 B)
  const u16* gsrc[6];
  int ldst[6];
#pragma unroll
  for (int i = 0; i < 6; ++i) {
    int c = tid + 512 * i;
    if (c < 2048) { int row = c >> 3, sl = c & 7;
      gsrc[i] = Ag + (size_t)(Am0 + row) * DDIM + ((sl ^ (row & 7)) << 3);
    } else { int cb = c - 2048, row = cb >> 3, sl = cb & 7;
      gsrc[i] = Bg + (size_t)(Bn0 + row) * DDIM + ((sl ^ (row & 7)) << 3);
    }
    ldst[i] = c << 3;
  }
  auto STAGE = [&](int t) {
    const int k0 = t << 6;
    u16* lb = lds + (t % 3) * 24576;
#pragma unroll
    for (int i = 0; i < 6; ++i) stage16(gsrc[i] + k0, lb + ldst[i]);
  };

  f32x4 acc[4][4] = {};
  const int NT = DDIM / 64;   // 16

  STAGE(0); STAGE(1);
  asm volatile("s_waitcnt vmcnt(6)" ::: "memory");
  __builtin_amdgcn_s_barrier();

  for (int t = 0; t < NT; ++t) {
    if (t + 2 < NT) STAGE(t + 2);
    const u16* lb = lds + (t % 3) * 24576;
    bf16x8 af[2][4], bf[2][4];
#pragma unroll
    for (int ks = 0; ks < 2; ++ks) {
#pragma unroll
      for (int m = 0; m < 4; ++m) {
        int row = wr * 64 + m * 16 + l15;
        int sl = ((ks << 2) | lkq) ^ (row & 7);
        af[ks][m] = *(const bf16x8*)&lb[row * 64 + (sl << 3)];
      }
#pragma unroll
      for (int n = 0; n < 4; ++n) {
        int row = wc * 64 + n * 16 + l15;
        int sl = ((ks << 2) | lkq) ^ (row & 7);
        bf[ks][n] = *(const bf16x8*)&lb[16384 + row * 64 + (sl << 3)];
      }
    }
    __builtin_amdgcn_s_setprio(1);
#pragma unroll
    for (int ks = 0; ks < 2; ++ks)
#pragma unroll
      for (int m = 0; m < 4; ++m)
#pragma unroll
        for (int n = 0; n < 4; ++n)
          acc[m][n] = __builtin_amdgcn_mfma_f32_16x16x32_bf16(af[ks][m], bf[ks][n], acc[m][n], 0, 0, 0);
    __builtin_amdgcn_s_setprio(0);
    if (t < NT - 1) {
      asm volatile("s_waitcnt lgkmcnt(0)" ::: "memory");
      __builtin_amdgcn_sched_barrier(0);
      if (t + 2 < NT) asm volatile("s_waitcnt vmcnt(6)" ::: "memory");
      else            asm volatile("s_waitcnt vmcnt(0)" ::: "memory");
      __builtin_amdgcn_s_barrier();
    }
  }

  // epilogue: fragment pair (2j, 2j+1) = (g, v) for the same H-column
  const float s_e = scale[e];
  const int hcb = nt * 64 + wc * 32;   // H-col base within expert
#pragma unroll
  for (int m = 0; m < 4; ++m) {
#pragma unroll
    for (int r = 0; r < 4; ++r) {
      const int t = Am0 + wr * 64 + m * 16 + lkq * 4 + r;
      const float dv = disp[t * NEXP + e];
      const float cv = comb[t * NEXP + e];
      const float s = (dv > 0.0f) ? cv * s_e : 0.0f;
#pragma unroll
      for (int j = 0; j < 2; ++j) {
        const float g = acc[m][2 * j][r];
        const float v = acc[m][2 * j + 1][r];
        const float ge = 0.5f * g * (1.0f + erff(g * 0.70710678f));
        h[(size_t)t * KTOT + e * HDIM + hcb + j * 16 + l15] = f2bf(ge * v * s);
      }
    }
  }
}

// ---------------- GEMM B: P[kz] = h[T][EH] @ woT2[D][EH]^T (split-K) ----------------
__global__ void __launch_bounds__(512, 2)
gemm_out_kernel(const u16* __restrict__ hb, const u16* __restrict__ woT2,
                float* __restrict__ P) {
  __shared__ u16 lds[3 * 24576];

  const int bid = blockIdx.x;          // nwg = 256
  const int wg = (bid & 7) * 32 + (bid >> 3);
  const int kz = wg >> 6;              // 0..3
  const int nt = (wg >> 3) & 7;        // D-tile (128)
  const int mt = wg & 7;               // token-tile (256)

  const int tid = threadIdx.x;
  const int lane = tid & 63;
  const int wave = tid >> 6;
  const int wr = wave >> 1;
  const int wc = wave & 1;
  const int l15 = lane & 15;
  const int lkq = lane >> 4;

  const int Am0 = mt * 256;
  const int Bn0 = nt * 128;
  const int kbase = kz * (KTOT / NSPLIT);   // 8192 per split

  const u16* gsrc[6];
  int ldst[6];
#pragma unroll
  for (int i = 0; i < 6; ++i) {
    int c = tid + 512 * i;
    if (c < 2048) { int row = c >> 3, sl = c & 7;
      gsrc[i] = hb + (size_t)(Am0 + row) * KTOT + kbase + ((sl ^ (row & 7)) << 3);
    } else { int cb = c - 2048, row = cb >> 3, sl = cb & 7;
      gsrc[i] = woT2 + (size_t)(Bn0 + row) * KTOT + kbase + ((sl ^ (row & 7)) << 3);
    }
    ldst[i] = c << 3;
  }
  auto STAGE = [&](int t) {
    const int k0 = t << 6;
    u16* lb = lds + (t % 3) * 24576;
#pragma unroll
    for (int i = 0; i < 6; ++i) stage16(gsrc[i] + k0, lb + ldst[i]);
  };

  f32x4 acc[4][4] = {};
  const int NT = (KTOT / NSPLIT) / 64;   // 128

  STAGE(0); STAGE(1);
  asm volatile("s_waitcnt vmcnt(6)" ::: "memory");
  __builtin_amdgcn_s_barrier();

  for (int t = 0; t < NT; ++t) {
    if (t + 2 < NT) STAGE(t + 2);
    const u16* lb = lds + (t % 3) * 24576;
    bf16x8 af[2][4], bf[2][4];
#pragma unroll
    for (int ks = 0; ks < 2; ++ks) {
#pragma unroll
      for (int m = 0; m < 4; ++m) {
        int row = wr * 64 + m * 16 + l15;
        int sl = ((ks << 2) | lkq) ^ (row & 7);
        af[ks][m] = *(const bf16x8*)&lb[row * 64 + (sl << 3)];
      }
#pragma unroll
      for (int n = 0; n < 4; ++n) {
        int row = wc * 64 + n * 16 + l15;
        int sl = ((ks << 2) | lkq) ^ (row & 7);
        bf[ks][n] = *(const bf16x8*)&lb[16384 + row * 64 + (sl << 3)];
      }
    }
    __builtin_amdgcn_s_setprio(1);
#pragma unroll
    for (int ks = 0; ks < 2; ++ks)
#pragma unroll
      for (int m = 0; m < 4; ++m)
#pragma unroll
        for (int n = 0; n < 4; ++n)
          acc[m][n] = __builtin_amdgcn_mfma_f32_16x16x32_bf16(af[ks][m], bf[ks][n], acc[m][n], 0, 0, 0);
    __builtin_amdgcn_s_setprio(0);
    if (t < NT - 1) {
      asm volatile("s_waitcnt lgkmcnt(0)" ::: "memory");
      __builtin_amdgcn_sched_barrier(0);
      if (t + 2 < NT) asm volatile("s_waitcnt vmcnt(6)" ::: "memory");
      else            asm volatile("s_waitcnt vmcnt(0)" ::: "memory");
      __builtin_amdgcn_s_barrier();
    }
  }

  float* Pp = P + (size_t)kz * (T_TOK * DDIM);
#pragma unroll
  for (int m = 0; m < 4; ++m) {
#pragma unroll
    for (int r = 0; r < 4; ++r) {
      const int t = Am0 + wr * 64 + m * 16 + lkq * 4 + r;
#pragma unroll
      for (int n = 0; n < 4; ++n)
        Pp[(size_t)t * DDIM + Bn0 + wc * 64 + n * 16 + l15] = acc[m][n][r];
    }
  }
}

// ---------------- final: out = sum of NSPLIT partials ----------------
__global__ void reduce_out_kernel(const float* __restrict__ P, float* __restrict__ out) {
  int i = blockIdx.x * 256 + threadIdx.x;
  float4 a = ((const float4*)P)[i];
#pragma unroll
  for (int s = 1; s < NSPLIT; ++s) {
    float4 b = ((const float4*)P)[i + s * (T_TOK * DDIM / 4)];
    a.x += b.x; a.y += b.y; a.z += b.z; a.w += b.w;
  }
  ((float4*)out)[i] = a;
}

extern "C" void kernel_launch(void* const* d_in, const int* in_sizes, int n_in,
                              void* d_out, int out_size, void* d_ws, size_t ws_size,
                              hipStream_t stream) {
  const float* tokens = (const float*)d_in[0];
  const float* disp   = (const float*)d_in[1];
  const float* comb   = (const float*)d_in[2];
  const float* Wg     = (const float*)d_in[3];
  const float* Wv     = (const float*)d_in[4];
  const float* Wo     = (const float*)d_in[5];
  const float* scale  = (const float*)d_in[6];
  float* out = (float*)d_out;

  char* ws = (char*)d_ws;
  const size_t MB = 1024 * 1024;
  u16* xb    = (u16*)(ws);              // 4 MB   [T][D] bf16
  u16* wgvT  = (u16*)(ws + 4   * MB);   // 128 MB [E][8192][D] interleaved g/v
  u16* woT2  = (u16*)(ws + 132 * MB);   // 64 MB  [D][E*H]
  u16* hbuf  = (u16*)(ws + 196 * MB);   // 128 MB [T][E*H]
  float* P   = (float*)(ws + 324 * MB); // 32 MB  NSPLIT x [T][D] fp32

  cvt_x_kernel<<<1024, 256, 0, stream>>>(tokens, xb);
  transpose_all_kernel<<<24576, 256, 0, stream>>>(Wg, Wv, Wo, wgvT, woT2);
  gemm_gv_kernel<<<4096, 512, 0, stream>>>(xb, wgvT, disp, comb, scale, hbuf);
  gemm_out_kernel<<<256, 512, 0, stream>>>(hbuf, woT2, P);
  reduce_out_kernel<<<2048, 256, 0, stream>>>(P, out);
}

// Round 4
// 555.305 us; speedup vs baseline: 1.5940x; 1.0616x over previous
//
#include <hip/hip_runtime.h>
#include <math.h>

#define T_TOK 2048
#define DDIM 1024
#define HDIM 4096
#define NEXP 8
#define NPRIME 8192            // 2*HDIM interleaved g/v cols per expert
#define KTOT (NEXP * HDIM)     // 32768
#define NSPLIT 8

typedef unsigned short u16;
typedef __attribute__((ext_vector_type(4))) float f32x4;
typedef __attribute__((ext_vector_type(8))) __bf16 bf16x8;
typedef __attribute__((ext_vector_type(8))) unsigned short u16x8;
typedef __attribute__((ext_vector_type(4))) unsigned short u16x4;

__device__ __forceinline__ u16 f2bf(float f) {
  unsigned int u = __builtin_bit_cast(unsigned int, f);
  u += 0x7fffu + ((u >> 16) & 1u);   // round-to-nearest-even
  return (u16)(u >> 16);
}

__device__ __forceinline__ void stage16(const u16* g, u16* l) {
  __builtin_amdgcn_global_load_lds((__attribute__((address_space(1))) void*)g,
                                   (__attribute__((address_space(3))) void*)l,
                                   16, 0, 0);
}

// ---------------- prep: x fp32 -> bf16 ----------------
__global__ void cvt_x_kernel(const float* __restrict__ x, u16* __restrict__ xb) {
  int i = (blockIdx.x * 256 + threadIdx.x) * 8;
  float4 a = *(const float4*)(x + i);
  float4 b = *(const float4*)(x + i + 4);
  u16x8 o;
  o[0] = f2bf(a.x); o[1] = f2bf(a.y); o[2] = f2bf(a.z); o[3] = f2bf(a.w);
  o[4] = f2bf(b.x); o[5] = f2bf(b.y); o[6] = f2bf(b.z); o[7] = f2bf(b.w);
  *(u16x8*)(xb + i) = o;
}

// ---------------- prep: transpose+cvt all experts ----------------
__global__ void transpose_all_kernel(const float* __restrict__ Wg,
                                     const float* __restrict__ Wv,
                                     const float* __restrict__ Wo,
                                     u16* __restrict__ wgvT, u16* __restrict__ woT2) {
  __shared__ float lds[64][65];
  const int bid = blockIdx.x;           // 24576 = 8e * 3mat * 1024 tiles
  const int e = bid / 3072;
  const int r = bid % 3072;
  const int which = r >> 10;            // 0=Wg 1=Wv 2=Wo
  const int tt = r & 1023;
  const float* src; int R, C;
  if (which == 2) { src = Wo + (size_t)e * HDIM * DDIM; R = HDIM; C = DDIM; }
  else            { src = (which ? Wv : Wg) + (size_t)e * DDIM * HDIM; R = DDIM; C = HDIM; }
  const int nrt = R >> 6;
  const int r0 = (tt % nrt) << 6, c0 = (tt / nrt) << 6;
  const int tid = threadIdx.x;
#pragma unroll
  for (int i = 0; i < 4; ++i) {
    int f4 = tid + 256 * i;
    int row = f4 >> 4, c4 = (f4 & 15) << 2;
    float4 v = *(const float4*)(src + (size_t)(r0 + row) * C + c0 + c4);
    lds[row][c4] = v.x; lds[row][c4 + 1] = v.y; lds[row][c4 + 2] = v.z; lds[row][c4 + 3] = v.w;
  }
  __syncthreads();
#pragma unroll
  for (int i = 0; i < 4; ++i) {
    int f4 = tid + 256 * i;
    int cc = f4 >> 4, r4 = (f4 & 15) << 2;
    u16x4 o;
    o[0] = f2bf(lds[r4][cc]);     o[1] = f2bf(lds[r4 + 1][cc]);
    o[2] = f2bf(lds[r4 + 2][cc]); o[3] = f2bf(lds[r4 + 3][cc]);
    u16* dst;
    if (which == 2) {
      dst = woT2 + (size_t)(c0 + cc) * KTOT + e * HDIM + r0 + r4;
    } else {
      int h = c0 + cc;
      int rowp = ((h >> 4) << 5) + which * 16 + (h & 15);
      dst = wgvT + (size_t)e * NPRIME * DDIM + (size_t)rowp * DDIM + r0 + r4;
    }
    *(u16x4*)dst = o;
  }
}

// =================================================================
// GEMM core: BM=256, BN=256, BK=64, 8 waves (2M x 4N), wave tile 128x64.
// 2 LDS slots (64 KB each): A [256][64] + B [256][64], XOR-8 slot swizzle
// (linear dest for global_load_lds; inverse-swizzled global source; swizzled
// ds_read). 4 phases per K-tile by (m-half h, ksub j); in-place quadrant
// replacement prefetch; one vmcnt(2) per tile; raw s_barrier per phase.
// =================================================================

template<int KS>
__device__ __forceinline__ void stageA_half(const u16* Ab, int Am0, int tk,
                                            u16* slot, int tid, int h) {
#pragma unroll
  for (int i = 0; i < 2; ++i) {
    int ca = tid + i * 512;
    int rowi = ca >> 3, sl = ca & 7;
    int row = (rowi & 63) + h * 64 + (rowi >> 6) * 128;
    const u16* g = Ab + (size_t)(Am0 + row) * KS + tk + ((sl ^ (row & 7)) << 3);
    stage16(g, slot + ((row << 3) + sl) * 8);
  }
}
template<int KS>
__device__ __forceinline__ void stageB_full(const u16* Bb, int Bn0, int tk,
                                            u16* slot, int tid) {
#pragma unroll
  for (int i = 0; i < 4; ++i) {
    int cb = tid + i * 512;
    int row = cb >> 3, sl = cb & 7;
    const u16* g = Bb + (size_t)(Bn0 + row) * KS + tk + ((sl ^ (row & 7)) << 3);
    stage16(g, slot + 16384 + cb * 8);
  }
}

__device__ __forceinline__ bf16x8 ldsA(const u16* slot, int row, int j, int lkq) {
  int sl = ((j << 2) | lkq) ^ (row & 7);
  return *(const bf16x8*)(slot + row * 64 + sl * 8);
}
__device__ __forceinline__ bf16x8 ldsB(const u16* slot, int row, int j, int lkq) {
  int sl = ((j << 2) | lkq) ^ (row & 7);
  return *(const bf16x8*)(slot + 16384 + row * 64 + sl * 8);
}

template<int KS>
__device__ __forceinline__ void gemm_loop(const u16* Ab, const u16* Bb,
                                          int Am0, int Bn0, int kbase, int NT,
                                          u16* lds, int tid, f32x4 (&acc)[8][4]) {
  const int lane = tid & 63;
  const int wave = tid >> 6;
  const int wm = wave >> 2;       // 0..1
  const int wn = wave & 3;        // 0..3
  const int l15 = lane & 15;
  const int lkq = lane >> 4;

  u16* slot0 = lds;
  u16* slot1 = lds + 32768;

  // prologue: tile0 full + tile1's A-h0; wait leaves 2 in flight
  stageA_half<KS>(Ab, Am0, kbase, slot0, tid, 0);
  stageA_half<KS>(Ab, Am0, kbase, slot0, tid, 1);
  stageB_full<KS>(Bb, Bn0, kbase, slot0, tid);
  stageA_half<KS>(Ab, Am0, kbase + 64, slot1, tid, 0);
  asm volatile("s_waitcnt vmcnt(2)" ::: "memory");
  asm volatile("s_barrier" ::: "memory");

#pragma unroll 1
  for (int t = 0; t < NT; ++t) {
    u16* s  = lds + (t & 1) * 32768;
    u16* s2 = lds + ((t & 1) ^ 1) * 32768;
    bf16x8 af[4], bfr[2][4];

    // ---- phase 1: h=0, j=0 (+ prefetch A-h1[t+1], B[t+1] into other slot)
    if (t + 1 < NT) {
      stageA_half<KS>(Ab, Am0, kbase + (t + 1) * 64, s2, tid, 1);
      stageB_full<KS>(Bb, Bn0, kbase + (t + 1) * 64, s2, tid);
    }
#pragma unroll
    for (int mf = 0; mf < 4; ++mf) af[mf] = ldsA(s, wm * 128 + mf * 16 + l15, 0, lkq);
#pragma unroll
    for (int nf = 0; nf < 4; ++nf) bfr[0][nf] = ldsB(s, wn * 64 + nf * 16 + l15, 0, lkq);
    __builtin_amdgcn_s_setprio(1);
#pragma unroll
    for (int mf = 0; mf < 4; ++mf)
#pragma unroll
      for (int nf = 0; nf < 4; ++nf)
        acc[mf][nf] = __builtin_amdgcn_mfma_f32_16x16x32_bf16(af[mf], bfr[0][nf], acc[mf][nf], 0, 0, 0);
    __builtin_amdgcn_s_setprio(0);
    asm volatile("s_barrier" ::: "memory");

    // ---- phase 2: h=1, j=0
#pragma unroll
    for (int mf = 0; mf < 4; ++mf) af[mf] = ldsA(s, wm * 128 + 64 + mf * 16 + l15, 0, lkq);
    __builtin_amdgcn_s_setprio(1);
#pragma unroll
    for (int mf = 0; mf < 4; ++mf)
#pragma unroll
      for (int nf = 0; nf < 4; ++nf)
        acc[4 + mf][nf] = __builtin_amdgcn_mfma_f32_16x16x32_bf16(af[mf], bfr[0][nf], acc[4 + mf][nf], 0, 0, 0);
    __builtin_amdgcn_s_setprio(0);
    asm volatile("s_barrier" ::: "memory");

    // ---- phase 3: h=0, j=1
#pragma unroll
    for (int mf = 0; mf < 4; ++mf) af[mf] = ldsA(s, wm * 128 + mf * 16 + l15, 1, lkq);
#pragma unroll
    for (int nf = 0; nf < 4; ++nf) bfr[1][nf] = ldsB(s, wn * 64 + nf * 16 + l15, 1, lkq);
    __builtin_amdgcn_s_setprio(1);
#pragma unroll
    for (int mf = 0; mf < 4; ++mf)
#pragma unroll
      for (int nf = 0; nf < 4; ++nf)
        acc[mf][nf] = __builtin_amdgcn_mfma_f32_16x16x32_bf16(af[mf], bfr[1][nf], acc[mf][nf], 0, 0, 0);
    __builtin_amdgcn_s_setprio(0);
    asm volatile("s_barrier" ::: "memory");

    // ---- phase 4: h=1, j=1 (+ prefetch A-h0[t+2] in place; counted vmcnt)
    if (t + 2 < NT) stageA_half<KS>(Ab, Am0, kbase + (t + 2) * 64, s, tid, 0);
#pragma unroll
    for (int mf = 0; mf < 4; ++mf) af[mf] = ldsA(s, wm * 128 + 64 + mf * 16 + l15, 1, lkq);
    __builtin_amdgcn_s_setprio(1);
#pragma unroll
    for (int mf = 0; mf < 4; ++mf)
#pragma unroll
      for (int nf = 0; nf < 4; ++nf)
        acc[4 + mf][nf] = __builtin_amdgcn_mfma_f32_16x16x32_bf16(af[mf], bfr[1][nf], acc[4 + mf][nf], 0, 0, 0);
    __builtin_amdgcn_s_setprio(0);
    if (t + 2 < NT)       { asm volatile("s_waitcnt vmcnt(2)" ::: "memory"); }
    else if (t + 2 == NT) { asm volatile("s_waitcnt vmcnt(0)" ::: "memory"); }
    asm volatile("s_barrier" ::: "memory");
  }
}

// ---------------- GEMM A: h = (gelu(x@Wg) * (x@Wv)) * scale * cw ----------------
__global__ void __launch_bounds__(512, 2)
gemm_gv_kernel(const u16* __restrict__ xb, const u16* __restrict__ wgvT,
               const float* __restrict__ disp, const float* __restrict__ comb,
               const float* __restrict__ scale, u16* __restrict__ h) {
  __shared__ u16 lds[65536];

  // XCD swizzle: 2048 wgs, expert e -> XCD e
  const int bid = blockIdx.x;
  const int wg = (bid & 7) * 256 + (bid >> 3);
  const int e  = wg >> 8;
  const int rr = wg & 255;
  const int nt = rr >> 3;          // 0..31 (N' tiles of 256)
  const int mt = rr & 7;           // 0..7  (M tiles of 256)

  const int tid = threadIdx.x;
  const int lane = tid & 63;
  const int wave = tid >> 6;
  const int wm = wave >> 2, wn = wave & 3;
  const int l15 = lane & 15, lkq = lane >> 4;

  const u16* Bb = wgvT + (size_t)e * NPRIME * DDIM;
  const int Am0 = mt * 256;
  const int Bn0 = nt * 256;

  f32x4 acc[8][4] = {};
  gemm_loop<DDIM>(xb, Bb, Am0, Bn0, 0, DDIM / 64, lds, tid, acc);

  const float s_e = scale[e];
  const int hbase = nt * 128 + wn * 32;   // H-col base within expert
#pragma unroll
  for (int a = 0; a < 8; ++a) {
#pragma unroll
    for (int r = 0; r < 4; ++r) {
      const int t = Am0 + wm * 128 + a * 16 + lkq * 4 + r;
      const float dv = disp[t * NEXP + e];
      const float cv = comb[t * NEXP + e];
      const float s = (dv > 0.0f) ? cv * s_e : 0.0f;
#pragma unroll
      for (int jj = 0; jj < 2; ++jj) {
        const float g = acc[a][2 * jj][r];
        const float v = acc[a][2 * jj + 1][r];
        const float ge = 0.5f * g * (1.0f + erff(g * 0.70710678f));
        h[(size_t)t * KTOT + e * HDIM + hbase + jj * 16 + l15] = f2bf(ge * v * s);
      }
    }
  }
}

// ---------------- GEMM B: P[kz] = h[T][EH] @ woT2[D][EH]^T (split-K 8) ----------------
__global__ void __launch_bounds__(512, 2)
gemm_out_kernel(const u16* __restrict__ hb, const u16* __restrict__ woT2,
                float* __restrict__ P) {
  __shared__ u16 lds[65536];

  const int bid = blockIdx.x;          // 256 wgs
  const int wg = (bid & 7) * 32 + (bid >> 3);
  const int kz = wg >> 5;              // 0..7, one per XCD
  const int rr = wg & 31;
  const int nt = rr >> 3;              // 0..3 (D tiles of 256)
  const int mt = rr & 7;               // 0..7 (token tiles of 256)

  const int tid = threadIdx.x;
  const int lane = tid & 63;
  const int wave = tid >> 6;
  const int wm = wave >> 2, wn = wave & 3;
  const int l15 = lane & 15, lkq = lane >> 4;

  const int Am0 = mt * 256;
  const int Bn0 = nt * 256;
  const int kbase = kz * (KTOT / NSPLIT);   // 4096 per split

  f32x4 acc[8][4] = {};
  gemm_loop<KTOT>(hb, woT2, Am0, Bn0, kbase, (KTOT / NSPLIT) / 64, lds, tid, acc);

  float* Pp = P + (size_t)kz * (T_TOK * DDIM);
#pragma unroll
  for (int a = 0; a < 8; ++a) {
#pragma unroll
    for (int r = 0; r < 4; ++r) {
      const int t = Am0 + wm * 128 + a * 16 + lkq * 4 + r;
#pragma unroll
      for (int nf = 0; nf < 4; ++nf)
        Pp[(size_t)t * DDIM + Bn0 + wn * 64 + nf * 16 + l15] = acc[a][nf][r];
    }
  }
}

// ---------------- final: out = sum of NSPLIT partials ----------------
__global__ void reduce_out_kernel(const float* __restrict__ P, float* __restrict__ out) {
  int i = blockIdx.x * 256 + threadIdx.x;
  float4 a = ((const float4*)P)[i];
#pragma unroll
  for (int s = 1; s < NSPLIT; ++s) {
    float4 b = ((const float4*)P)[i + s * (T_TOK * DDIM / 4)];
    a.x += b.x; a.y += b.y; a.z += b.z; a.w += b.w;
  }
  ((float4*)out)[i] = a;
}

extern "C" void kernel_launch(void* const* d_in, const int* in_sizes, int n_in,
                              void* d_out, int out_size, void* d_ws, size_t ws_size,
                              hipStream_t stream) {
  const float* tokens = (const float*)d_in[0];
  const float* disp   = (const float*)d_in[1];
  const float* comb   = (const float*)d_in[2];
  const float* Wg     = (const float*)d_in[3];
  const float* Wv     = (const float*)d_in[4];
  const float* Wo     = (const float*)d_in[5];
  const float* scale  = (const float*)d_in[6];
  float* out = (float*)d_out;

  char* ws = (char*)d_ws;
  const size_t MB = 1024 * 1024;
  u16* xb    = (u16*)(ws);              // 4 MB   [T][D] bf16
  u16* wgvT  = (u16*)(ws + 4   * MB);   // 128 MB [E][8192][D] interleaved g/v
  u16* woT2  = (u16*)(ws + 132 * MB);   // 64 MB  [D][E*H]
  u16* hbuf  = (u16*)(ws + 196 * MB);   // 128 MB [T][E*H]
  float* P   = (float*)(ws + 324 * MB); // 64 MB  NSPLIT x [T][D] fp32

  cvt_x_kernel<<<1024, 256, 0, stream>>>(tokens, xb);
  transpose_all_kernel<<<24576, 256, 0, stream>>>(Wg, Wv, Wo, wgvT, woT2);
  gemm_gv_kernel<<<2048, 512, 0, stream>>>(xb, wgvT, disp, comb, scale, hbuf);
  gemm_out_kernel<<<256, 512, 0, stream>>>(hbuf, woT2, P);
  reduce_out_kernel<<<2048, 256, 0, stream>>>(P, out);
}

// Round 5
// 555.242 us; speedup vs baseline: 1.5942x; 1.0001x over previous
//
#include <hip/hip_runtime.h>
#include <math.h>

#define T_TOK 2048
#define DDIM 1024
#define HDIM 4096
#define NEXP 8
#define NPRIME 8192            // 2*HDIM interleaved g/v cols per expert
#define KTOT (NEXP * HDIM)     // 32768
#define NSPLIT 8

typedef unsigned short u16;
typedef __attribute__((ext_vector_type(4))) float f32x4;
typedef __attribute__((ext_vector_type(8))) __bf16 bf16x8;
typedef __attribute__((ext_vector_type(8))) unsigned short u16x8;
typedef __attribute__((ext_vector_type(4))) unsigned short u16x4;

__device__ __forceinline__ u16 f2bf(float f) {
  unsigned int u = __builtin_bit_cast(unsigned int, f);
  u += 0x7fffu + ((u >> 16) & 1u);   // round-to-nearest-even
  return (u16)(u >> 16);
}

__device__ __forceinline__ void stage16(const u16* g, u16* l) {
  __builtin_amdgcn_global_load_lds((__attribute__((address_space(1))) void*)g,
                                   (__attribute__((address_space(3))) void*)l,
                                   16, 0, 0);
}

// ---------------- prep: x fp32 -> bf16 ----------------
__global__ void cvt_x_kernel(const float* __restrict__ x, u16* __restrict__ xb) {
  int i = (blockIdx.x * 256 + threadIdx.x) * 8;
  float4 a = *(const float4*)(x + i);
  float4 b = *(const float4*)(x + i + 4);
  u16x8 o;
  o[0] = f2bf(a.x); o[1] = f2bf(a.y); o[2] = f2bf(a.z); o[3] = f2bf(a.w);
  o[4] = f2bf(b.x); o[5] = f2bf(b.y); o[6] = f2bf(b.z); o[7] = f2bf(b.w);
  *(u16x8*)(xb + i) = o;
}

// ---------------- prep: transpose+cvt all experts ----------------
__global__ void transpose_all_kernel(const float* __restrict__ Wg,
                                     const float* __restrict__ Wv,
                                     const float* __restrict__ Wo,
                                     u16* __restrict__ wgvT, u16* __restrict__ woT2) {
  __shared__ float lds[64][65];
  const int bid = blockIdx.x;           // 24576 = 8e * 3mat * 1024 tiles
  const int e = bid / 3072;
  const int r = bid % 3072;
  const int which = r >> 10;            // 0=Wg 1=Wv 2=Wo
  const int tt = r & 1023;
  const float* src; int R, C;
  if (which == 2) { src = Wo + (size_t)e * HDIM * DDIM; R = HDIM; C = DDIM; }
  else            { src = (which ? Wv : Wg) + (size_t)e * DDIM * HDIM; R = DDIM; C = HDIM; }
  const int nrt = R >> 6;
  const int r0 = (tt % nrt) << 6, c0 = (tt / nrt) << 6;
  const int tid = threadIdx.x;
#pragma unroll
  for (int i = 0; i < 4; ++i) {
    int f4 = tid + 256 * i;
    int row = f4 >> 4, c4 = (f4 & 15) << 2;
    float4 v = *(const float4*)(src + (size_t)(r0 + row) * C + c0 + c4);
    lds[row][c4] = v.x; lds[row][c4 + 1] = v.y; lds[row][c4 + 2] = v.z; lds[row][c4 + 3] = v.w;
  }
  __syncthreads();
#pragma unroll
  for (int i = 0; i < 4; ++i) {
    int f4 = tid + 256 * i;
    int cc = f4 >> 4, r4 = (f4 & 15) << 2;
    u16x4 o;
    o[0] = f2bf(lds[r4][cc]);     o[1] = f2bf(lds[r4 + 1][cc]);
    o[2] = f2bf(lds[r4 + 2][cc]); o[3] = f2bf(lds[r4 + 3][cc]);
    u16* dst;
    if (which == 2) {
      dst = woT2 + (size_t)(c0 + cc) * KTOT + e * HDIM + r0 + r4;
    } else {
      int h = c0 + cc;
      int rowp = ((h >> 4) << 5) + which * 16 + (h & 15);
      dst = wgvT + (size_t)e * NPRIME * DDIM + (size_t)rowp * DDIM + r0 + r4;
    }
    *(u16x4*)dst = o;
  }
}

// =================================================================
// GEMM core: BM=256, BN=256, BK=64, 8 waves (2M x 4N), wave tile 128x64.
// m201-style 4-phase-per-K-tile schedule, 2 LDS slots (64 KB each),
// XOR-8 swizzle (inverse-swizzled global source, swizzled ds_read).
// Stage units (16 KB, 2 gload_lds/thread): SA0 = A rows {0-63,128-191},
// SA1 = +64; SB0 = B rows {0-31,64-95,128-159,192-223}, SB1 = +32.
// Per phase: {ds_read ; stage unit(t+1) ; s_barrier ; lgkmcnt(0) ;
//  16 MFMA ; counted vmcnt ; s_barrier}.  vmcnt(4) steady (never 0).
// =================================================================

__device__ __forceinline__ bf16x8 ldsA(const u16* slot, int row, int j, int lkq) {
  int sl = ((j << 2) | lkq) ^ (row & 7);
  return *(const bf16x8*)(slot + row * 64 + sl * 8);
}
__device__ __forceinline__ bf16x8 ldsB(const u16* slot, int row, int j, int lkq) {
  int sl = ((j << 2) | lkq) ^ (row & 7);
  return *(const bf16x8*)(slot + 16384 + row * 64 + sl * 8);
}

template<int KS>
__device__ __forceinline__ void gemm_loop(const u16* Ab, const u16* Bb,
                                          int Am0, int Bn0, int kbase, int NT,
                                          u16* lds, int tid, f32x4 (&acc)[8][4]) {
  const int lane = tid & 63;
  const int wave = tid >> 6;
  const int wm = wave >> 2, wn = wave & 3;
  const int l15 = lane & 15, lkq = lane >> 4;

  const int sl = tid & 7, rw = tid >> 3;          // rw 0..63
  const int slx = (sl ^ (rw & 7)) << 3;           // inverse-swizzled k-offset
  const int rb = (rw & 31) + ((rw >> 5) << 6);    // B base row
  const u16* pA = Ab + (size_t)(Am0 + rw) * KS + kbase + slx;
  const u16* pB = Bb + (size_t)(Bn0 + rb) * KS + kbase + slx;
  const int dA = rw * 64 + sl * 8;
  const int dB = 16384 + rb * 64 + sl * 8;

  auto SA0 = [&](int k, u16* slot) {
    stage16(pA + k, slot + dA);
    stage16(pA + (size_t)128 * KS + k, slot + dA + 128 * 64);
  };
  auto SA1 = [&](int k, u16* slot) {
    stage16(pA + (size_t)64 * KS + k, slot + dA + 64 * 64);
    stage16(pA + (size_t)192 * KS + k, slot + dA + 192 * 64);
  };
  auto SB0 = [&](int k, u16* slot) {
    stage16(pB + k, slot + dB);
    stage16(pB + (size_t)128 * KS + k, slot + dB + 128 * 64);
  };
  auto SB1 = [&](int k, u16* slot) {
    stage16(pB + (size_t)32 * KS + k, slot + dB + 32 * 64);
    stage16(pB + (size_t)160 * KS + k, slot + dB + 160 * 64);
  };

  // prologue: all of tile 0 into slot 0 (SA0,SB0 first -> vmcnt(4) drains them)
  SA0(0, lds); SB0(0, lds); SB1(0, lds); SA1(0, lds);
  asm volatile("s_waitcnt vmcnt(4)" ::: "memory");
  __builtin_amdgcn_s_barrier();

#pragma unroll 1
  for (int t = 0; t < NT; ++t) {
    u16* s  = lds + (t & 1) * 32768;
    u16* s2 = lds + ((t & 1) ^ 1) * 32768;
    const int kn = (t + 1) << 6;
    const bool more = (t + 1 < NT);
    bf16x8 af[4][2], bfr[4][2];

    // ---------- phase 0: read A-mh0 + B-nh0 ; stage SA0(t+1) ; MFMA m0-3 x n0-1
#pragma unroll
    for (int mf = 0; mf < 4; ++mf)
#pragma unroll
      for (int ks = 0; ks < 2; ++ks)
        af[mf][ks] = ldsA(s, wm * 128 + mf * 16 + l15, ks, lkq);
#pragma unroll
    for (int nf = 0; nf < 2; ++nf)
#pragma unroll
      for (int ks = 0; ks < 2; ++ks)
        bfr[nf][ks] = ldsB(s, wn * 64 + nf * 16 + l15, ks, lkq);
    if (more) SA0(kn, s2);
    __builtin_amdgcn_sched_barrier(0);
    __builtin_amdgcn_s_barrier();
    asm volatile("s_waitcnt lgkmcnt(0)" ::: "memory");
    __builtin_amdgcn_sched_barrier(0);
    __builtin_amdgcn_s_setprio(1);
#pragma unroll
    for (int ks = 0; ks < 2; ++ks)
#pragma unroll
      for (int mf = 0; mf < 4; ++mf)
#pragma unroll
        for (int nf = 0; nf < 2; ++nf)
          acc[mf][nf] = __builtin_amdgcn_mfma_f32_16x16x32_bf16(af[mf][ks], bfr[nf][ks], acc[mf][nf], 0, 0, 0);
    __builtin_amdgcn_s_setprio(0);
    if (more) { asm volatile("s_waitcnt vmcnt(4)" ::: "memory"); }
    else      { asm volatile("s_waitcnt vmcnt(2)" ::: "memory"); }
    __builtin_amdgcn_s_barrier();
    __builtin_amdgcn_sched_barrier(0);

    // ---------- phase 1: read B-nh1 ; stage SB0(t+1) ; MFMA m0-3 x n2-3
#pragma unroll
    for (int nf = 2; nf < 4; ++nf)
#pragma unroll
      for (int ks = 0; ks < 2; ++ks)
        bfr[nf][ks] = ldsB(s, wn * 64 + nf * 16 + l15, ks, lkq);
    if (more) SB0(kn, s2);
    __builtin_amdgcn_sched_barrier(0);
    __builtin_amdgcn_s_barrier();
    asm volatile("s_waitcnt lgkmcnt(0)" ::: "memory");
    __builtin_amdgcn_sched_barrier(0);
    __builtin_amdgcn_s_setprio(1);
#pragma unroll
    for (int ks = 0; ks < 2; ++ks)
#pragma unroll
      for (int mf = 0; mf < 4; ++mf)
#pragma unroll
        for (int nf = 2; nf < 4; ++nf)
          acc[mf][nf] = __builtin_amdgcn_mfma_f32_16x16x32_bf16(af[mf][ks], bfr[nf][ks], acc[mf][nf], 0, 0, 0);
    __builtin_amdgcn_s_setprio(0);
    if (more) { asm volatile("s_waitcnt vmcnt(4)" ::: "memory"); }
    else      { asm volatile("s_waitcnt vmcnt(0)" ::: "memory"); }
    __builtin_amdgcn_s_barrier();
    __builtin_amdgcn_sched_barrier(0);

    // ---------- phase 2: read A-mh1 ; stage SB1(t+1) ; MFMA m4-7 x n0-1
#pragma unroll
    for (int mf = 0; mf < 4; ++mf)
#pragma unroll
      for (int ks = 0; ks < 2; ++ks)
        af[mf][ks] = ldsA(s, wm * 128 + 64 + mf * 16 + l15, ks, lkq);
    if (more) SB1(kn, s2);
    __builtin_amdgcn_sched_barrier(0);
    __builtin_amdgcn_s_barrier();
    asm volatile("s_waitcnt lgkmcnt(0)" ::: "memory");
    __builtin_amdgcn_sched_barrier(0);
    __builtin_amdgcn_s_setprio(1);
#pragma unroll
    for (int ks = 0; ks < 2; ++ks)
#pragma unroll
      for (int mf = 0; mf < 4; ++mf)
#pragma unroll
        for (int nf = 0; nf < 2; ++nf)
          acc[4 + mf][nf] = __builtin_amdgcn_mfma_f32_16x16x32_bf16(af[mf][ks], bfr[nf][ks], acc[4 + mf][nf], 0, 0, 0);
    __builtin_amdgcn_s_setprio(0);
    __builtin_amdgcn_s_barrier();
    __builtin_amdgcn_sched_barrier(0);

    // ---------- phase 3: stage SA1(t+1) ; MFMA m4-7 x n2-3 (all regs cached)
    if (more) SA1(kn, s2);
    __builtin_amdgcn_s_setprio(1);
#pragma unroll
    for (int ks = 0; ks < 2; ++ks)
#pragma unroll
      for (int mf = 0; mf < 4; ++mf)
#pragma unroll
        for (int nf = 2; nf < 4; ++nf)
          acc[4 + mf][nf] = __builtin_amdgcn_mfma_f32_16x16x32_bf16(af[mf][ks], bfr[nf][ks], acc[4 + mf][nf], 0, 0, 0);
    __builtin_amdgcn_s_setprio(0);
    if (more) { asm volatile("s_waitcnt vmcnt(4)" ::: "memory"); }
    __builtin_amdgcn_s_barrier();
    __builtin_amdgcn_sched_barrier(0);
  }
}

// ---------------- GEMM A: h = (gelu(x@Wg) * (x@Wv)) * scale * cw ----------------
__global__ void __launch_bounds__(512, 2)
gemm_gv_kernel(const u16* __restrict__ xb, const u16* __restrict__ wgvT,
               const float* __restrict__ disp, const float* __restrict__ comb,
               const float* __restrict__ scale, u16* __restrict__ h) {
  __shared__ u16 lds[65536];

  // XCD swizzle: 2048 wgs, expert e -> XCD e
  const int bid = blockIdx.x;
  const int wg = (bid & 7) * 256 + (bid >> 3);
  const int e  = wg >> 8;
  const int rr = wg & 255;
  const int nt = rr >> 3;          // 0..31 (N' tiles of 256)
  const int mt = rr & 7;           // 0..7  (M tiles of 256)

  const int tid = threadIdx.x;
  const int lane = tid & 63;
  const int wave = tid >> 6;
  const int wm = wave >> 2, wn = wave & 3;
  const int l15 = lane & 15, lkq = lane >> 4;

  const u16* Bb = wgvT + (size_t)e * NPRIME * DDIM;
  const int Am0 = mt * 256;
  const int Bn0 = nt * 256;

  f32x4 acc[8][4] = {};
  gemm_loop<DDIM>(xb, Bb, Am0, Bn0, 0, DDIM / 64, lds, tid, acc);

  const float s_e = scale[e];
  const int hbase = nt * 128 + wn * 32;   // H-col base within expert
#pragma unroll
  for (int a = 0; a < 8; ++a) {
#pragma unroll
    for (int r = 0; r < 4; ++r) {
      const int t = Am0 + wm * 128 + a * 16 + lkq * 4 + r;
      const float dv = disp[t * NEXP + e];
      const float cv = comb[t * NEXP + e];
      const float s = (dv > 0.0f) ? cv * s_e : 0.0f;
#pragma unroll
      for (int jj = 0; jj < 2; ++jj) {
        const float g = acc[a][2 * jj][r];
        const float v = acc[a][2 * jj + 1][r];
        const float ge = 0.5f * g * (1.0f + erff(g * 0.70710678f));
        h[(size_t)t * KTOT + e * HDIM + hbase + jj * 16 + l15] = f2bf(ge * v * s);
      }
    }
  }
}

// ---------------- GEMM B: P[kz] = h[T][EH] @ woT2[D][EH]^T (split-K 8) ----------------
__global__ void __launch_bounds__(512, 2)
gemm_out_kernel(const u16* __restrict__ hb, const u16* __restrict__ woT2,
                float* __restrict__ P) {
  __shared__ u16 lds[65536];

  const int bid = blockIdx.x;          // 256 wgs
  const int wg = (bid & 7) * 32 + (bid >> 3);
  const int kz = wg >> 5;              // 0..7, one per XCD
  const int rr = wg & 31;
  const int nt = rr >> 3;              // 0..3 (D tiles of 256)
  const int mt = rr & 7;               // 0..7 (token tiles of 256)

  const int tid = threadIdx.x;
  const int lane = tid & 63;
  const int wave = tid >> 6;
  const int wm = wave >> 2, wn = wave & 3;
  const int l15 = lane & 15, lkq = lane >> 4;

  const int Am0 = mt * 256;
  const int Bn0 = nt * 256;
  const int kbase = kz * (KTOT / NSPLIT);   // 4096 per split

  f32x4 acc[8][4] = {};
  gemm_loop<KTOT>(hb, woT2, Am0, Bn0, kbase, (KTOT / NSPLIT) / 64, lds, tid, acc);

  float* Pp = P + (size_t)kz * (T_TOK * DDIM);
#pragma unroll
  for (int a = 0; a < 8; ++a) {
#pragma unroll
    for (int r = 0; r < 4; ++r) {
      const int t = Am0 + wm * 128 + a * 16 + lkq * 4 + r;
#pragma unroll
      for (int nf = 0; nf < 4; ++nf)
        Pp[(size_t)t * DDIM + Bn0 + wn * 64 + nf * 16 + l15] = acc[a][nf][r];
    }
  }
}

// ---------------- final: out = sum of NSPLIT partials ----------------
__global__ void reduce_out_kernel(const float* __restrict__ P, float* __restrict__ out) {
  int i = blockIdx.x * 256 + threadIdx.x;
  float4 a = ((const float4*)P)[i];
#pragma unroll
  for (int s = 1; s < NSPLIT; ++s) {
    float4 b = ((const float4*)P)[i + s * (T_TOK * DDIM / 4)];
    a.x += b.x; a.y += b.y; a.z += b.z; a.w += b.w;
  }
  ((float4*)out)[i] = a;
}

extern "C" void kernel_launch(void* const* d_in, const int* in_sizes, int n_in,
                              void* d_out, int out_size, void* d_ws, size_t ws_size,
                              hipStream_t stream) {
  const float* tokens = (const float*)d_in[0];
  const float* disp   = (const float*)d_in[1];
  const float* comb   = (const float*)d_in[2];
  const float* Wg     = (const float*)d_in[3];
  const float* Wv     = (const float*)d_in[4];
  const float* Wo     = (const float*)d_in[5];
  const float* scale  = (const float*)d_in[6];
  float* out = (float*)d_out;

  char* ws = (char*)d_ws;
  const size_t MB = 1024 * 1024;
  u16* xb    = (u16*)(ws);              // 4 MB   [T][D] bf16
  u16* wgvT  = (u16*)(ws + 4   * MB);   // 128 MB [E][8192][D] interleaved g/v
  u16* woT2  = (u16*)(ws + 132 * MB);   // 64 MB  [D][E*H]
  u16* hbuf  = (u16*)(ws + 196 * MB);   // 128 MB [T][E*H]
  float* P   = (float*)(ws + 324 * MB); // 64 MB  NSPLIT x [T][D] fp32

  cvt_x_kernel<<<1024, 256, 0, stream>>>(tokens, xb);
  transpose_all_kernel<<<24576, 256, 0, stream>>>(Wg, Wv, Wo, wgvT, woT2);
  gemm_gv_kernel<<<2048, 512, 0, stream>>>(xb, wgvT, disp, comb, scale, hbuf);
  gemm_out_kernel<<<256, 512, 0, stream>>>(hbuf, woT2, P);
  reduce_out_kernel<<<2048, 256, 0, stream>>>(P, out);
}